// Round 7
// baseline (146.394 us; speedup 1.0000x reference)
//
#include <hip/hip_runtime.h>

typedef _Float16 half8 __attribute__((ext_vector_type(8)));
typedef float f32x4 __attribute__((ext_vector_type(4)));

#define IN_F 4096
#define OUT_F 4096
#define RANK 64
#define M_TOT 8192
#define KCHUNK 1024
#define NKC (IN_F / KCHUNK)
#define MROWS 8   // rows per block (grid = 1024 -> 4 blocks/CU)

// 2 aligned groups of 4: 2:4 soft-threshold, scale, cast f16. VALIDATED (r4/r5).
__device__ __forceinline__ half8 thresh8(const float* __restrict__ p, float scale) {
    half8 h;
    #pragma unroll
    for (int g = 0; g < 2; ++g) {
        f32x4 v = *(const f32x4*)(p + 4 * g);
        float m0 = fabsf(v[0]), m1 = fabsf(v[1]), m2 = fabsf(v[2]), m3 = fabsf(v[3]);
        float lo1 = fminf(m0, m1), hi1 = fmaxf(m0, m1);
        float lo2 = fminf(m2, m3), hi2 = fmaxf(m2, m3);
        float t = fminf(fmaxf(lo1, lo2), fminf(hi1, hi2)); // 2nd-smallest magnitude
        h[4 * g + 0] = (_Float16)(copysignf(fmaxf(m0 - t, 0.0f), v[0]) * scale);
        h[4 * g + 1] = (_Float16)(copysignf(fmaxf(m1 - t, 0.0f), v[1]) * scale);
        h[4 * g + 2] = (_Float16)(copysignf(fmaxf(m2 - t, 0.0f), v[2]) * scale);
        h[4 * g + 3] = (_Float16)(copysignf(fmaxf(m3 - t, 0.0f), v[3]) * scale);
    }
    return h;
}

// ---------------------------------------------------------------------------
// prep: f16 sparse weights into d_ws (validated r6).
// ---------------------------------------------------------------------------
__global__ __launch_bounds__(256) void prep_kernel(
    const float* __restrict__ w_in, const float* __restrict__ w_out,
    const float* __restrict__ s_in_p, const float* __restrict__ s_out_p,
    _Float16* __restrict__ sw_in, _Float16* __restrict__ sw_out)
{
    const int tid = blockIdx.x * 256 + threadIdx.x;
    const int HALF = RANK * IN_F / 8;     // 32768
    const float* src; _Float16* dst; float sc; int g;
    if (tid < HALF) { src = w_in;  dst = sw_in;  sc = *s_in_p;  g = tid; }
    else            { src = w_out; dst = sw_out; sc = *s_out_p; g = tid - HALF; }
    half8 h = thresh8(src + (size_t)g * 8, sc);
    *(half8*)(dst + (size_t)g * 8) = h;
}

// ---------------------------------------------------------------------------
// Main fused kernel. Block = MROWS(8) M-rows, 4 waves, grid = 1024.
// Same validated dataflow as r6, but half the M-tile for 2x grid:
//  - MFMA A rows 8-15 mirror rows 0-7 (row&7 LDS read); D rows 8-15 discarded.
//  - Phase-2 stores predicated to local rows 0-7 (kg<2).
// MFMA 16x16x32_f16: A/B lane l elem j -> (free = l&15, k = (l>>4)*8 + j);
// D lane l reg r -> (Afree = (l>>4)*4 + r, Bfree = l&15).
// ---------------------------------------------------------------------------
__global__ __launch_bounds__(256) void loro_main(
    const float* __restrict__ x, const _Float16* __restrict__ sw_in,
    const _Float16* __restrict__ sw_out, const float* __restrict__ bias,
    float* __restrict__ out)
{
    __shared__ _Float16 xh[2][MROWS][KCHUNK];   // 32 KiB, swizzled 16B blocks
    __shared__ _Float16 xpl[16][RANK];          // 2 KiB

    const int t    = threadIdx.x;
    const int wave = t >> 6;
    const int lane = t & 63;
    const int row  = lane & 15;
    const int arow = row & 7;        // A-operand source row (rows 8-15 mirror 0-7)
    const int kg   = lane >> 4;
    const int m0   = blockIdx.x * MROWS;

    // staging map: thread t, iter i -> row r = i*2 + (t>>7), 16B-block skb = t&127
    const int sr  = t >> 7;
    const int skb = t & 127;

    f32x4 ra[4], rb[4];

    auto issue = [&](int kc) {                    // global loads only (no use)
        #pragma unroll
        for (int i = 0; i < 4; ++i) {
            const float* src = x + (size_t)(m0 + i * 2 + sr) * IN_F + kc + skb * 8;
            ra[i] = *(const f32x4*)src;
            rb[i] = *(const f32x4*)(src + 4);
        }
    };
    auto cstore = [&](int buf) {                  // convert + swizzled b128 store
        #pragma unroll
        for (int i = 0; i < 4; ++i) {
            const int r = i * 2 + sr;
            half8 h;
            #pragma unroll
            for (int j = 0; j < 4; ++j) {
                h[j]     = (_Float16)ra[i][j];
                h[j + 4] = (_Float16)rb[i][j];
            }
            *(half8*)&xh[buf][r][(skb ^ r) << 3] = h;   // r = r&7 (MROWS=8)
        }
    };

    // ---------------- phase 1 ----------------
    const _Float16* wr = sw_in + (size_t)(wave * 16 + row) * IN_F + kg * 8;
    f32x4 acc1 = {0.f, 0.f, 0.f, 0.f};

    issue(0);
    cstore(0);
    __syncthreads();
    int cur = 0;
    for (int kci = 0; kci < NKC; ++kci) {
        if (kci + 1 < NKC) issue((kci + 1) * KCHUNK);   // overlap with consume
        const int kc = kci * KCHUNK;
        #pragma unroll 4
        for (int k0 = 0; k0 < KCHUNK; k0 += 64) {
            const int kb = (k0 >> 3) + kg;
            half8 alo = *(const half8*)&xh[cur][arow][(kb       ^ arow) << 3];
            half8 ahi = *(const half8*)&xh[cur][arow][((kb + 4) ^ arow) << 3];
            half8 blo = *(const half8*)(wr + kc + k0);
            half8 bhi = *(const half8*)(wr + kc + k0 + 32);
            acc1 = __builtin_amdgcn_mfma_f32_16x16x32_f16(alo, blo, acc1, 0, 0, 0);
            acc1 = __builtin_amdgcn_mfma_f32_16x16x32_f16(ahi, bhi, acc1, 0, 0, 0);
        }
        if (kci + 1 < NKC) cstore(cur ^ 1);
        __syncthreads();
        cur ^= 1;
    }

    // D rows 0-15; rows 8-15 are duplicates of 0-7 (harmless to store).
    #pragma unroll
    for (int r = 0; r < 4; ++r)
        xpl[kg * 4 + r][wave * 16 + row] = (_Float16)acc1[r];
    __syncthreads();

    // ---------------- phase 2 (validated structure) ----------------
    const half8 a_lo = *(const half8*)&xpl[row][kg * 8];
    const half8 a_hi = *(const half8*)&xpl[row][kg * 8 + 32];
    const float scaling = 1.0f / 64.0f;

    for (int c = 0; c < 16; ++c) {
        f32x4 acc[4] = {{0.f,0.f,0.f,0.f},{0.f,0.f,0.f,0.f},
                        {0.f,0.f,0.f,0.f},{0.f,0.f,0.f,0.f}};
        #pragma unroll
        for (int nt = 0; nt < 4; ++nt) {
            const _Float16* wp = sw_out
                + (size_t)(c * 256 + wave * 64 + nt * 16 + row) * RANK + kg * 8;
            half8 blo = *(const half8*)wp;
            half8 bhi = *(const half8*)(wp + 32);
            acc[nt] = __builtin_amdgcn_mfma_f32_16x16x32_f16(a_lo, blo, acc[nt], 0, 0, 0);
            acc[nt] = __builtin_amdgcn_mfma_f32_16x16x32_f16(a_hi, bhi, acc[nt], 0, 0, 0);
        }
        if (kg < 2) {                               // local rows 0-7 only
            #pragma unroll
            for (int nt = 0; nt < 4; ++nt) {
                const int col = c * 256 + wave * 64 + nt * 16 + row;
                const float b = bias[col];
                #pragma unroll
                for (int r = 0; r < 4; ++r)
                    out[(size_t)(m0 + kg * 4 + r) * OUT_F + col] = (acc[nt][r] + b) * scaling;
            }
        }
    }
}

// ---------------------------------------------------------------------------
// Fallback: round-5 kernel VERBATIM (passed at 155 us). Used if ws too small.
// ---------------------------------------------------------------------------
__global__ __launch_bounds__(256) void loro_fallback(
    const float* __restrict__ x, const float* __restrict__ w_in,
    const float* __restrict__ w_out, const float* __restrict__ bias,
    const float* __restrict__ s_in_p, const float* __restrict__ s_out_p,
    float* __restrict__ out)
{
    __shared__ _Float16 xh[16][KCHUNK];
    __shared__ _Float16 xpl[16][RANK];

    const int t    = threadIdx.x;
    const int wave = t >> 6;
    const int lane = t & 63;
    const int row  = lane & 15;
    const int kg   = lane >> 4;
    const int m0   = blockIdx.x * 16;
    const float s_in  = *s_in_p;
    const float s_out = *s_out_p;

    f32x4 acc1 = {0.f, 0.f, 0.f, 0.f};
    const float* wr = w_in + (size_t)(wave * 16 + row) * IN_F + kg * 8;

    for (int kc = 0; kc < IN_F; kc += KCHUNK) {
        __syncthreads();
        #pragma unroll
        for (int i = 0; i < 8; ++i) {
            const int f  = i * 2048 + t * 8;
            const int r  = f >> 10;
            const int cl = f & (KCHUNK - 1);
            const float* src = x + (size_t)(m0 + r) * IN_F + kc + cl;
            f32x4 a = *(const f32x4*)src;
            f32x4 b = *(const f32x4*)(src + 4);
            #pragma unroll
            for (int j = 0; j < 4; ++j) {
                xh[r][cl + j]     = (_Float16)a[j];
                xh[r][cl + 4 + j] = (_Float16)b[j];
            }
        }
        __syncthreads();

        #pragma unroll 4
        for (int k0 = 0; k0 < KCHUNK; k0 += 64) {
            half8 alo = *(const half8*)&xh[row][k0 + kg * 8];
            half8 ahi = *(const half8*)&xh[row][k0 + kg * 8 + 32];
            half8 blo = thresh8(wr + kc + k0,      s_in);
            half8 bhi = thresh8(wr + kc + k0 + 32, s_in);
            acc1 = __builtin_amdgcn_mfma_f32_16x16x32_f16(alo, blo, acc1, 0, 0, 0);
            acc1 = __builtin_amdgcn_mfma_f32_16x16x32_f16(ahi, bhi, acc1, 0, 0, 0);
        }
    }

    #pragma unroll
    for (int r = 0; r < 4; ++r)
        xpl[kg * 4 + r][wave * 16 + row] = (_Float16)acc1[r];
    __syncthreads();

    const half8 a_lo = *(const half8*)&xpl[row][kg * 8];
    const half8 a_hi = *(const half8*)&xpl[row][kg * 8 + 32];
    const float scaling = 1.0f / 64.0f;

    for (int c = 0; c < 16; ++c) {
        f32x4 acc[4] = {{0.f,0.f,0.f,0.f},{0.f,0.f,0.f,0.f},
                        {0.f,0.f,0.f,0.f},{0.f,0.f,0.f,0.f}};
        #pragma unroll
        for (int nt = 0; nt < 4; ++nt) {
            const float* wp = w_out
                + (size_t)(c * 256 + wave * 64 + nt * 16 + row) * RANK + kg * 8;
            half8 blo = thresh8(wp,      s_out);
            half8 bhi = thresh8(wp + 32, s_out);
            acc[nt] = __builtin_amdgcn_mfma_f32_16x16x32_f16(a_lo, blo, acc[nt], 0, 0, 0);
            acc[nt] = __builtin_amdgcn_mfma_f32_16x16x32_f16(a_hi, bhi, acc[nt], 0, 0, 0);
        }
        #pragma unroll
        for (int nt = 0; nt < 4; ++nt) {
            const int col = c * 256 + wave * 64 + nt * 16 + row;
            const float b = bias[col];
            #pragma unroll
            for (int r = 0; r < 4; ++r)
                out[(size_t)(m0 + kg * 4 + r) * OUT_F + col] = (acc[nt][r] + b) * scaling;
        }
    }
}

// ---------------------------------------------------------------------------
extern "C" void kernel_launch(void* const* d_in, const int* in_sizes, int n_in,
                              void* d_out, int out_size, void* d_ws, size_t ws_size,
                              hipStream_t stream) {
    (void)in_sizes; (void)n_in; (void)out_size;
    const float* x     = (const float*)d_in[0];
    const float* w_in  = (const float*)d_in[1];
    const float* w_out = (const float*)d_in[2];
    const float* bias  = (const float*)d_in[3];
    const float* s_in  = (const float*)d_in[4];
    const float* s_out = (const float*)d_in[5];

    const size_t need = (size_t)(RANK * IN_F + OUT_F * RANK) * sizeof(_Float16); // 1 MiB
    if (d_ws != nullptr && ws_size >= need) {
        _Float16* sw_in  = (_Float16*)d_ws;
        _Float16* sw_out = sw_in + (size_t)RANK * IN_F;
        prep_kernel<<<(RANK * IN_F + OUT_F * RANK) / 8 / 256, 256, 0, stream>>>(
            w_in, w_out, s_in, s_out, sw_in, sw_out);
        loro_main<<<M_TOT / MROWS, 256, 0, stream>>>(x, sw_in, sw_out, bias, (float*)d_out);
    } else {
        loro_fallback<<<M_TOT / 16, 256, 0, stream>>>(
            x, w_in, w_out, bias, s_in, s_out, (float*)d_out);
    }
}

// Round 8
// 98.997 us; speedup vs baseline: 1.4788x; 1.4788x over previous
//
#include <hip/hip_runtime.h>

typedef _Float16 half8 __attribute__((ext_vector_type(8)));
typedef float f32x4 __attribute__((ext_vector_type(4)));

#define IN_F 4096
#define OUT_F 4096
#define RANK 64
#define M_TOT 8192
#define KCHUNK 1024
#define NKC (IN_F / KCHUNK)
#define KSPLIT 4

// 2 aligned groups of 4: 2:4 soft-threshold, scale, cast f16. VALIDATED (r4/r5).
__device__ __forceinline__ half8 thresh8(const float* __restrict__ p, float scale) {
    half8 h;
    #pragma unroll
    for (int g = 0; g < 2; ++g) {
        f32x4 v = *(const f32x4*)(p + 4 * g);
        float m0 = fabsf(v[0]), m1 = fabsf(v[1]), m2 = fabsf(v[2]), m3 = fabsf(v[3]);
        float lo1 = fminf(m0, m1), hi1 = fmaxf(m0, m1);
        float lo2 = fminf(m2, m3), hi2 = fmaxf(m2, m3);
        float t = fminf(fmaxf(lo1, lo2), fminf(hi1, hi2)); // 2nd-smallest magnitude
        h[4 * g + 0] = (_Float16)(copysignf(fmaxf(m0 - t, 0.0f), v[0]) * scale);
        h[4 * g + 1] = (_Float16)(copysignf(fmaxf(m1 - t, 0.0f), v[1]) * scale);
        h[4 * g + 2] = (_Float16)(copysignf(fmaxf(m2 - t, 0.0f), v[2]) * scale);
        h[4 * g + 3] = (_Float16)(copysignf(fmaxf(m3 - t, 0.0f), v[3]) * scale);
    }
    return h;
}

// ---------------------------------------------------------------------------
// prep: f16 sparse weights into d_ws (validated r6).
// ---------------------------------------------------------------------------
__global__ __launch_bounds__(256) void prep_kernel(
    const float* __restrict__ w_in, const float* __restrict__ w_out,
    const float* __restrict__ s_in_p, const float* __restrict__ s_out_p,
    _Float16* __restrict__ sw_in, _Float16* __restrict__ sw_out)
{
    const int tid = blockIdx.x * 256 + threadIdx.x;
    const int HALF = RANK * IN_F / 8;     // 32768
    const float* src; _Float16* dst; float sc; int g;
    if (tid < HALF) { src = w_in;  dst = sw_in;  sc = *s_in_p;  g = tid; }
    else            { src = w_out; dst = sw_out; sc = *s_out_p; g = tid - HALF; }
    half8 h = thresh8(src + (size_t)g * 8, sc);
    *(half8*)(dst + (size_t)g * 8) = h;
}

// ---------------------------------------------------------------------------
// gemm1_ks: f32 K-partial of xp. Grid = 512 M-tiles x 4 K-slices = 2048.
// Block: 16 rows, 4 waves; block K-range = ks*1024..+1024; wave k-slice 256.
// x staged f32->f16 into swizzled LDS (validated r6 op); B from sw_in (d_ws);
// 4-wave partials LDS-reduced in fixed order -> xpp[ks][m][n] f32.
// MFMA 16x16x32_f16: A/B lane l elem j -> (free = l&15, k = (l>>4)*8 + j);
// D lane l reg r -> (Afree = (l>>4)*4 + r, Bfree = l&15).
// ---------------------------------------------------------------------------
__global__ __launch_bounds__(256) void gemm1_ks(
    const float* __restrict__ x, const _Float16* __restrict__ sw_in,
    float* __restrict__ xpp)
{
    __shared__ _Float16 xh[16][KCHUNK];   // 32 KiB (swizzled 16B blocks)
    __shared__ float red[KSPLIT][16][RANK]; // 16 KiB

    const int t    = threadIdx.x;
    const int wave = t >> 6;
    const int lane = t & 63;
    const int row  = lane & 15;
    const int kg   = lane >> 4;
    const int mt   = blockIdx.x >> 2;
    const int ks   = blockIdx.x & 3;
    const int m0   = mt * 16;
    const int kbase = ks * KCHUNK;

    // stage x[16][kbase..+1024] -> f16 LDS, swizzle 16B-block index by row&7
    {
        const int sr  = t >> 7;       // 0..1
        const int skb = t & 127;      // 16B-block column
        #pragma unroll
        for (int i = 0; i < 8; ++i) {
            const int r = i * 2 + sr;
            const float* src = x + (size_t)(m0 + r) * IN_F + kbase + skb * 8;
            f32x4 a = *(const f32x4*)src;
            f32x4 b = *(const f32x4*)(src + 4);
            half8 h;
            #pragma unroll
            for (int j = 0; j < 4; ++j) { h[j] = (_Float16)a[j]; h[j + 4] = (_Float16)b[j]; }
            *(half8*)&xh[r][(skb ^ (r & 7)) << 3] = h;
        }
    }
    __syncthreads();

    // wave's 256-k slice: 4 steps of 64
    f32x4 acc[4] = {{0.f,0.f,0.f,0.f},{0.f,0.f,0.f,0.f},
                    {0.f,0.f,0.f,0.f},{0.f,0.f,0.f,0.f}};
    const _Float16* wbase = sw_in + kbase + wave * 256 + kg * 8;
    #pragma unroll
    for (int s = 0; s < 4; ++s) {
        const int kb = wave * 32 + s * 8 + kg;
        half8 alo = *(const half8*)&xh[row][(kb       ^ (row & 7)) << 3];
        half8 ahi = *(const half8*)&xh[row][((kb + 4) ^ (row & 7)) << 3];
        #pragma unroll
        for (int nt = 0; nt < 4; ++nt) {
            const _Float16* wp = wbase + (size_t)(nt * 16 + row) * IN_F + s * 64;
            half8 blo = *(const half8*)wp;
            half8 bhi = *(const half8*)(wp + 32);
            acc[nt] = __builtin_amdgcn_mfma_f32_16x16x32_f16(alo, blo, acc[nt], 0, 0, 0);
            acc[nt] = __builtin_amdgcn_mfma_f32_16x16x32_f16(ahi, bhi, acc[nt], 0, 0, 0);
        }
    }

    #pragma unroll
    for (int nt = 0; nt < 4; ++nt)
        #pragma unroll
        for (int r = 0; r < 4; ++r)
            red[wave][kg * 4 + r][nt * 16 + row] = acc[nt][r];
    __syncthreads();

    for (int i = t; i < 16 * RANK; i += 256) {
        const int m = i >> 6, n = i & 63;
        float s = (red[0][m][n] + red[1][m][n]) + (red[2][m][n] + red[3][m][n]);
        xpp[((size_t)ks * M_TOT + m0 + m) * RANK + n] = s;
    }
}

// ---------------------------------------------------------------------------
// gemm2_big: out = (f16(sum xpp) @ sw_out^T + bias)/64.
// Grid = 512 M-tiles x 4 col-chunks(1024) = 2048. Block: 4 waves, wave = 256 cols.
// Partial sum in fixed order (matches full-f32-K reference within fp noise).
// ---------------------------------------------------------------------------
__global__ __launch_bounds__(256) void gemm2_big(
    const float* __restrict__ xpp, const _Float16* __restrict__ sw_out,
    const float* __restrict__ bias, float* __restrict__ out)
{
    __shared__ _Float16 xpl[16][RANK + 8];   // padded (bank spread), 16B-aligned rows

    const int t    = threadIdx.x;
    const int wave = t >> 6;
    const int lane = t & 63;
    const int row  = lane & 15;
    const int kg   = lane >> 4;
    const int mt   = blockIdx.x >> 2;
    const int nc   = blockIdx.x & 3;
    const int m0   = mt * 16;

    for (int i = t; i < 16 * RANK; i += 256) {
        const int m = i >> 6, n = i & 63;
        const size_t base = (size_t)(m0 + m) * RANK + n;
        const size_t S = (size_t)M_TOT * RANK;
        float s = (xpp[base] + xpp[S + base]) + (xpp[2 * S + base] + xpp[3 * S + base]);
        xpl[m][n] = (_Float16)s;
    }
    __syncthreads();

    const half8 a_lo = *(const half8*)&xpl[row][kg * 8];
    const half8 a_hi = *(const half8*)&xpl[row][kg * 8 + 32];
    const float scaling = 1.0f / 64.0f;

    #pragma unroll
    for (int c = 0; c < 4; ++c) {
        const int cg = nc * 1024 + wave * 256 + c * 64;
        f32x4 acc[4] = {{0.f,0.f,0.f,0.f},{0.f,0.f,0.f,0.f},
                        {0.f,0.f,0.f,0.f},{0.f,0.f,0.f,0.f}};
        #pragma unroll
        for (int nt = 0; nt < 4; ++nt) {
            const _Float16* wp = sw_out + (size_t)(cg + nt * 16 + row) * RANK + kg * 8;
            half8 blo = *(const half8*)wp;
            half8 bhi = *(const half8*)(wp + 32);
            acc[nt] = __builtin_amdgcn_mfma_f32_16x16x32_f16(a_lo, blo, acc[nt], 0, 0, 0);
            acc[nt] = __builtin_amdgcn_mfma_f32_16x16x32_f16(a_hi, bhi, acc[nt], 0, 0, 0);
        }
        #pragma unroll
        for (int nt = 0; nt < 4; ++nt) {
            const int col = cg + nt * 16 + row;
            const float b = bias[col];
            #pragma unroll
            for (int r = 0; r < 4; ++r)
                out[(size_t)(m0 + kg * 4 + r) * OUT_F + col] = (acc[nt][r] + b) * scaling;
        }
    }
}

// ---------------------------------------------------------------------------
// Mid tier: round-6 fused kernel VERBATIM (92 us total). Used if ws in [1,9) MB.
// ---------------------------------------------------------------------------
__global__ __launch_bounds__(256) void loro_fused16(
    const float* __restrict__ x, const _Float16* __restrict__ sw_in,
    const _Float16* __restrict__ sw_out, const float* __restrict__ bias,
    float* __restrict__ out)
{
    __shared__ _Float16 xh[2][16][KCHUNK];
    __shared__ _Float16 xpl[16][RANK];

    const int t    = threadIdx.x;
    const int wave = t >> 6;
    const int lane = t & 63;
    const int row  = lane & 15;
    const int kg   = lane >> 4;
    const int m0   = blockIdx.x * 16;

    const int sr  = t >> 7;
    const int skb = t & 127;

    f32x4 ra[8], rb[8];

    auto issue = [&](int kc) {
        #pragma unroll
        for (int i = 0; i < 8; ++i) {
            const float* src = x + (size_t)(m0 + i * 2 + sr) * IN_F + kc + skb * 8;
            ra[i] = *(const f32x4*)src;
            rb[i] = *(const f32x4*)(src + 4);
        }
    };
    auto cstore = [&](int buf) {
        #pragma unroll
        for (int i = 0; i < 8; ++i) {
            const int r = i * 2 + sr;
            half8 h;
            #pragma unroll
            for (int j = 0; j < 4; ++j) {
                h[j]     = (_Float16)ra[i][j];
                h[j + 4] = (_Float16)rb[i][j];
            }
            *(half8*)&xh[buf][r][(skb ^ (r & 7)) << 3] = h;
        }
    };

    const _Float16* wr = sw_in + (size_t)(wave * 16 + row) * IN_F + kg * 8;
    f32x4 acc1 = {0.f, 0.f, 0.f, 0.f};

    issue(0);
    cstore(0);
    __syncthreads();
    int cur = 0;
    for (int kci = 0; kci < NKC; ++kci) {
        if (kci + 1 < NKC) issue((kci + 1) * KCHUNK);
        const int kc = kci * KCHUNK;
        #pragma unroll 4
        for (int k0 = 0; k0 < KCHUNK; k0 += 64) {
            const int kb = (k0 >> 3) + kg;
            half8 alo = *(const half8*)&xh[cur][row][(kb       ^ (row & 7)) << 3];
            half8 ahi = *(const half8*)&xh[cur][row][((kb + 4) ^ (row & 7)) << 3];
            half8 blo = *(const half8*)(wr + kc + k0);
            half8 bhi = *(const half8*)(wr + kc + k0 + 32);
            acc1 = __builtin_amdgcn_mfma_f32_16x16x32_f16(alo, blo, acc1, 0, 0, 0);
            acc1 = __builtin_amdgcn_mfma_f32_16x16x32_f16(ahi, bhi, acc1, 0, 0, 0);
        }
        if (kci + 1 < NKC) cstore(cur ^ 1);
        __syncthreads();
        cur ^= 1;
    }

    #pragma unroll
    for (int r = 0; r < 4; ++r)
        xpl[kg * 4 + r][wave * 16 + row] = (_Float16)acc1[r];
    __syncthreads();

    const half8 a_lo = *(const half8*)&xpl[row][kg * 8];
    const half8 a_hi = *(const half8*)&xpl[row][kg * 8 + 32];
    const float scaling = 1.0f / 64.0f;

    for (int c = 0; c < 16; ++c) {
        f32x4 acc[4] = {{0.f,0.f,0.f,0.f},{0.f,0.f,0.f,0.f},
                        {0.f,0.f,0.f,0.f},{0.f,0.f,0.f,0.f}};
        #pragma unroll
        for (int nt = 0; nt < 4; ++nt) {
            const _Float16* wp = sw_out
                + (size_t)(c * 256 + wave * 64 + nt * 16 + row) * RANK + kg * 8;
            half8 blo = *(const half8*)wp;
            half8 bhi = *(const half8*)(wp + 32);
            acc[nt] = __builtin_amdgcn_mfma_f32_16x16x32_f16(a_lo, blo, acc[nt], 0, 0, 0);
            acc[nt] = __builtin_amdgcn_mfma_f32_16x16x32_f16(a_hi, bhi, acc[nt], 0, 0, 0);
        }
        #pragma unroll
        for (int nt = 0; nt < 4; ++nt) {
            const int col = c * 256 + wave * 64 + nt * 16 + row;
            const float b = bias[col];
            #pragma unroll
            for (int r = 0; r < 4; ++r)
                out[(size_t)(m0 + kg * 4 + r) * OUT_F + col] = (acc[nt][r] + b) * scaling;
        }
    }
}

// ---------------------------------------------------------------------------
// Fallback: round-5 kernel VERBATIM (155 us, no ws). Used if ws < 1 MB.
// ---------------------------------------------------------------------------
__global__ __launch_bounds__(256) void loro_fallback(
    const float* __restrict__ x, const float* __restrict__ w_in,
    const float* __restrict__ w_out, const float* __restrict__ bias,
    const float* __restrict__ s_in_p, const float* __restrict__ s_out_p,
    float* __restrict__ out)
{
    __shared__ _Float16 xh[16][KCHUNK];
    __shared__ _Float16 xpl[16][RANK];

    const int t    = threadIdx.x;
    const int wave = t >> 6;
    const int lane = t & 63;
    const int row  = lane & 15;
    const int kg   = lane >> 4;
    const int m0   = blockIdx.x * 16;
    const float s_in  = *s_in_p;
    const float s_out = *s_out_p;

    f32x4 acc1 = {0.f, 0.f, 0.f, 0.f};
    const float* wr = w_in + (size_t)(wave * 16 + row) * IN_F + kg * 8;

    for (int kc = 0; kc < IN_F; kc += KCHUNK) {
        __syncthreads();
        #pragma unroll
        for (int i = 0; i < 8; ++i) {
            const int f  = i * 2048 + t * 8;
            const int r  = f >> 10;
            const int cl = f & (KCHUNK - 1);
            const float* src = x + (size_t)(m0 + r) * IN_F + kc + cl;
            f32x4 a = *(const f32x4*)src;
            f32x4 b = *(const f32x4*)(src + 4);
            #pragma unroll
            for (int j = 0; j < 4; ++j) {
                xh[r][cl + j]     = (_Float16)a[j];
                xh[r][cl + 4 + j] = (_Float16)b[j];
            }
        }
        __syncthreads();

        #pragma unroll 4
        for (int k0 = 0; k0 < KCHUNK; k0 += 64) {
            half8 alo = *(const half8*)&xh[row][k0 + kg * 8];
            half8 ahi = *(const half8*)&xh[row][k0 + kg * 8 + 32];
            half8 blo = thresh8(wr + kc + k0,      s_in);
            half8 bhi = thresh8(wr + kc + k0 + 32, s_in);
            acc1 = __builtin_amdgcn_mfma_f32_16x16x32_f16(alo, blo, acc1, 0, 0, 0);
            acc1 = __builtin_amdgcn_mfma_f32_16x16x32_f16(ahi, bhi, acc1, 0, 0, 0);
        }
    }

    #pragma unroll
    for (int r = 0; r < 4; ++r)
        xpl[kg * 4 + r][wave * 16 + row] = (_Float16)acc1[r];
    __syncthreads();

    const half8 a_lo = *(const half8*)&xpl[row][kg * 8];
    const half8 a_hi = *(const half8*)&xpl[row][kg * 8 + 32];
    const float scaling = 1.0f / 64.0f;

    for (int c = 0; c < 16; ++c) {
        f32x4 acc[4] = {{0.f,0.f,0.f,0.f},{0.f,0.f,0.f,0.f},
                        {0.f,0.f,0.f,0.f},{0.f,0.f,0.f,0.f}};
        #pragma unroll
        for (int nt = 0; nt < 4; ++nt) {
            const float* wp = w_out
                + (size_t)(c * 256 + wave * 64 + nt * 16 + row) * RANK + kg * 8;
            half8 blo = thresh8(wp,      s_out);
            half8 bhi = thresh8(wp + 32, s_out);
            acc[nt] = __builtin_amdgcn_mfma_f32_16x16x32_f16(a_lo, blo, acc[nt], 0, 0, 0);
            acc[nt] = __builtin_amdgcn_mfma_f32_16x16x32_f16(a_hi, bhi, acc[nt], 0, 0, 0);
        }
        #pragma unroll
        for (int nt = 0; nt < 4; ++nt) {
            const int col = c * 256 + wave * 64 + nt * 16 + row;
            const float b = bias[col];
            #pragma unroll
            for (int r = 0; r < 4; ++r)
                out[(size_t)(m0 + kg * 4 + r) * OUT_F + col] = (acc[nt][r] + b) * scaling;
        }
    }
}

// ---------------------------------------------------------------------------
extern "C" void kernel_launch(void* const* d_in, const int* in_sizes, int n_in,
                              void* d_out, int out_size, void* d_ws, size_t ws_size,
                              hipStream_t stream) {
    (void)in_sizes; (void)n_in; (void)out_size;
    const float* x     = (const float*)d_in[0];
    const float* w_in  = (const float*)d_in[1];
    const float* w_out = (const float*)d_in[2];
    const float* bias  = (const float*)d_in[3];
    const float* s_in  = (const float*)d_in[4];
    const float* s_out = (const float*)d_in[5];

    const size_t need_sw   = (size_t)(RANK * IN_F + OUT_F * RANK) * sizeof(_Float16); // 1 MiB
    const size_t need_full = need_sw + (size_t)KSPLIT * M_TOT * RANK * sizeof(float); // 9 MiB

    if (d_ws != nullptr && ws_size >= need_full) {
        _Float16* sw_in  = (_Float16*)d_ws;
        _Float16* sw_out = sw_in + (size_t)RANK * IN_F;
        float*    xpp    = (float*)((char*)d_ws + need_sw);
        prep_kernel<<<(RANK * IN_F + OUT_F * RANK) / 8 / 256, 256, 0, stream>>>(
            w_in, w_out, s_in, s_out, sw_in, sw_out);
        gemm1_ks<<<(M_TOT / 16) * KSPLIT, 256, 0, stream>>>(x, sw_in, xpp);
        gemm2_big<<<(M_TOT / 16) * (OUT_F / 1024), 256, 0, stream>>>(
            xpp, sw_out, bias, (float*)d_out);
    } else if (d_ws != nullptr && ws_size >= need_sw) {
        _Float16* sw_in  = (_Float16*)d_ws;
        _Float16* sw_out = sw_in + (size_t)RANK * IN_F;
        prep_kernel<<<(RANK * IN_F + OUT_F * RANK) / 8 / 256, 256, 0, stream>>>(
            w_in, w_out, s_in, s_out, sw_in, sw_out);
        loro_fused16<<<M_TOT / 16, 256, 0, stream>>>(x, sw_in, sw_out, bias, (float*)d_out);
    } else {
        loro_fallback<<<M_TOT / 16, 256, 0, stream>>>(
            x, w_in, w_out, bias, s_in, s_out, (float*)d_out);
    }
}

// Round 9
// 90.629 us; speedup vs baseline: 1.6153x; 1.0923x over previous
//
#include <hip/hip_runtime.h>

typedef _Float16 half8 __attribute__((ext_vector_type(8)));
typedef float f32x4 __attribute__((ext_vector_type(4)));

#define IN_F 4096
#define OUT_F 4096
#define RANK 64
#define M_TOT 8192
#define KCHUNK 1024
#define NKC (IN_F / KCHUNK)

// 2 aligned groups of 4: 2:4 soft-threshold, scale, cast f16. VALIDATED (r4/r5).
__device__ __forceinline__ half8 thresh8(const float* __restrict__ p, float scale) {
    half8 h;
    #pragma unroll
    for (int g = 0; g < 2; ++g) {
        f32x4 v = *(const f32x4*)(p + 4 * g);
        float m0 = fabsf(v[0]), m1 = fabsf(v[1]), m2 = fabsf(v[2]), m3 = fabsf(v[3]);
        float lo1 = fminf(m0, m1), hi1 = fmaxf(m0, m1);
        float lo2 = fminf(m2, m3), hi2 = fmaxf(m2, m3);
        float t = fminf(fmaxf(lo1, lo2), fminf(hi1, hi2)); // 2nd-smallest magnitude
        h[4 * g + 0] = (_Float16)(copysignf(fmaxf(m0 - t, 0.0f), v[0]) * scale);
        h[4 * g + 1] = (_Float16)(copysignf(fmaxf(m1 - t, 0.0f), v[1]) * scale);
        h[4 * g + 2] = (_Float16)(copysignf(fmaxf(m2 - t, 0.0f), v[2]) * scale);
        h[4 * g + 3] = (_Float16)(copysignf(fmaxf(m3 - t, 0.0f), v[3]) * scale);
    }
    return h;
}

// ---------------------------------------------------------------------------
// prep: f16 sparse weights into d_ws (validated r6).
// ---------------------------------------------------------------------------
__global__ __launch_bounds__(256) void prep_kernel(
    const float* __restrict__ w_in, const float* __restrict__ w_out,
    const float* __restrict__ s_in_p, const float* __restrict__ s_out_p,
    _Float16* __restrict__ sw_in, _Float16* __restrict__ sw_out)
{
    const int tid = blockIdx.x * 256 + threadIdx.x;
    const int HALF = RANK * IN_F / 8;     // 32768
    const float* src; _Float16* dst; float sc; int g;
    if (tid < HALF) { src = w_in;  dst = sw_in;  sc = *s_in_p;  g = tid; }
    else            { src = w_out; dst = sw_out; sc = *s_out_p; g = tid - HALF; }
    half8 h = thresh8(src + (size_t)g * 8, sc);
    *(half8*)(dst + (size_t)g * 8) = h;
}

// ---------------------------------------------------------------------------
// Fused kernel v2 = r6 loro_fused16 with a coalesced phase-2 epilogue.
// Block = 16 M-rows, 4 waves, grid = 512.
// Phase 1 (r6 verbatim): x staged f32->f16 into double-buffered swizzled LDS;
//   wave w owns xp cols w*16..+15, full K; xp -> xpl f16.
// Phase 2 (NEW): wave w owns cols [w*1024, w*1024+1024), 8 groups of 128:
//   MFMA (2x 64-col chunks) -> +bias, *1/64 -> wave-private LDS transpose
//   buffer (8 KiB, overlaid on dead xh; intra-wave, no block sync) ->
//   read back row-major -> global_store_dwordx4 (512B contiguous segments).
// MFMA 16x16x32_f16: A/B lane l elem j -> (free = l&15, k = (l>>4)*8 + j);
// D lane l reg r -> (Afree = (l>>4)*4 + r, Bfree = l&15).
// ---------------------------------------------------------------------------
__global__ __launch_bounds__(256) void loro_fused_v2(
    const float* __restrict__ x, const _Float16* __restrict__ sw_in,
    const _Float16* __restrict__ sw_out, const float* __restrict__ bias,
    float* __restrict__ out)
{
    __shared__ __align__(16) char smem[2 * 16 * KCHUNK * 2];   // 64 KiB
    __shared__ _Float16 xpl[16][RANK];                          // 2 KiB
    auto xh = (_Float16 (*)[16][KCHUNK])smem;

    const int t    = threadIdx.x;
    const int wave = t >> 6;
    const int lane = t & 63;
    const int row  = lane & 15;
    const int kg   = lane >> 4;
    const int m0   = blockIdx.x * 16;

    const int sr  = t >> 7;
    const int skb = t & 127;

    f32x4 ra[8], rb[8];

    auto issue = [&](int kc) {
        #pragma unroll
        for (int i = 0; i < 8; ++i) {
            const float* src = x + (size_t)(m0 + i * 2 + sr) * IN_F + kc + skb * 8;
            ra[i] = *(const f32x4*)src;
            rb[i] = *(const f32x4*)(src + 4);
        }
    };
    auto cstore = [&](int buf) {
        #pragma unroll
        for (int i = 0; i < 8; ++i) {
            const int r = i * 2 + sr;
            half8 h;
            #pragma unroll
            for (int j = 0; j < 4; ++j) {
                h[j]     = (_Float16)ra[i][j];
                h[j + 4] = (_Float16)rb[i][j];
            }
            *(half8*)&xh[buf][r][(skb ^ (r & 7)) << 3] = h;
        }
    };

    // ---------------- phase 1 (r6 verbatim) ----------------
    const _Float16* wr = sw_in + (size_t)(wave * 16 + row) * IN_F + kg * 8;
    f32x4 acc1 = {0.f, 0.f, 0.f, 0.f};

    issue(0);
    cstore(0);
    __syncthreads();
    int cur = 0;
    for (int kci = 0; kci < NKC; ++kci) {
        if (kci + 1 < NKC) issue((kci + 1) * KCHUNK);
        const int kc = kci * KCHUNK;
        #pragma unroll 4
        for (int k0 = 0; k0 < KCHUNK; k0 += 64) {
            const int kb = (k0 >> 3) + kg;
            half8 alo = *(const half8*)&xh[cur][row][(kb       ^ (row & 7)) << 3];
            half8 ahi = *(const half8*)&xh[cur][row][((kb + 4) ^ (row & 7)) << 3];
            half8 blo = *(const half8*)(wr + kc + k0);
            half8 bhi = *(const half8*)(wr + kc + k0 + 32);
            acc1 = __builtin_amdgcn_mfma_f32_16x16x32_f16(alo, blo, acc1, 0, 0, 0);
            acc1 = __builtin_amdgcn_mfma_f32_16x16x32_f16(ahi, bhi, acc1, 0, 0, 0);
        }
        if (kci + 1 < NKC) cstore(cur ^ 1);
        __syncthreads();
        cur ^= 1;
    }

    #pragma unroll
    for (int r = 0; r < 4; ++r)
        xpl[kg * 4 + r][wave * 16 + row] = (_Float16)acc1[r];
    __syncthreads();   // after this, xh is dead -> reuse as transpose buffers

    // ---------------- phase 2 (coalesced epilogue) ----------------
    const half8 a_lo = *(const half8*)&xpl[row][kg * 8];
    const half8 a_hi = *(const half8*)&xpl[row][kg * 8 + 32];
    const float scaling = 1.0f / 64.0f;

    float* tb = (float*)smem + wave * 2048;        // wave-private 8 KiB [16][128]
    const int ncol0 = wave * 1024;                  // wave's contiguous col slice

    for (int g = 0; g < 8; ++g) {
        const int gc = ncol0 + g * 128;
        // compute 2 chunks of 64 cols, deposit into tb with bias+scaling
        #pragma unroll
        for (int c2 = 0; c2 < 2; ++c2) {
            const int cg = gc + c2 * 64;
            f32x4 acc[4] = {{0.f,0.f,0.f,0.f},{0.f,0.f,0.f,0.f},
                            {0.f,0.f,0.f,0.f},{0.f,0.f,0.f,0.f}};
            #pragma unroll
            for (int nt = 0; nt < 4; ++nt) {
                const _Float16* wp = sw_out + (size_t)(cg + nt * 16 + row) * RANK + kg * 8;
                half8 blo = *(const half8*)wp;
                half8 bhi = *(const half8*)(wp + 32);
                acc[nt] = __builtin_amdgcn_mfma_f32_16x16x32_f16(a_lo, blo, acc[nt], 0, 0, 0);
                acc[nt] = __builtin_amdgcn_mfma_f32_16x16x32_f16(a_hi, bhi, acc[nt], 0, 0, 0);
            }
            #pragma unroll
            for (int nt = 0; nt < 4; ++nt) {
                const float b = bias[cg + nt * 16 + row];
                #pragma unroll
                for (int r = 0; r < 4; ++r)
                    tb[(kg * 4 + r) * 128 + c2 * 64 + nt * 16 + row] =
                        (acc[nt][r] + b) * scaling;
            }
        }
        // read back row-major, store 512B-contiguous segments (2 rows/instr)
        #pragma unroll
        for (int i = 0; i < 8; ++i) {
            const int s   = i * 64 + lane;       // 0..511
            const int orow = s >> 5;             // 0..15
            const int c4  = s & 31;              // f32x4 slot within 128 cols
            f32x4 v = *(const f32x4*)&tb[orow * 128 + c4 * 4];
            *(f32x4*)&out[(size_t)(m0 + orow) * OUT_F + gc + c4 * 4] = v;
        }
    }
}

// ---------------------------------------------------------------------------
// Fallback: round-5 kernel VERBATIM (155 us, no ws). Used if ws < 1 MB.
// ---------------------------------------------------------------------------
__global__ __launch_bounds__(256) void loro_fallback(
    const float* __restrict__ x, const float* __restrict__ w_in,
    const float* __restrict__ w_out, const float* __restrict__ bias,
    const float* __restrict__ s_in_p, const float* __restrict__ s_out_p,
    float* __restrict__ out)
{
    __shared__ _Float16 xh[16][KCHUNK];
    __shared__ _Float16 xpl[16][RANK];

    const int t    = threadIdx.x;
    const int wave = t >> 6;
    const int lane = t & 63;
    const int row  = lane & 15;
    const int kg   = lane >> 4;
    const int m0   = blockIdx.x * 16;
    const float s_in  = *s_in_p;
    const float s_out = *s_out_p;

    f32x4 acc1 = {0.f, 0.f, 0.f, 0.f};
    const float* wr = w_in + (size_t)(wave * 16 + row) * IN_F + kg * 8;

    for (int kc = 0; kc < IN_F; kc += KCHUNK) {
        __syncthreads();
        #pragma unroll
        for (int i = 0; i < 8; ++i) {
            const int f  = i * 2048 + t * 8;
            const int r  = f >> 10;
            const int cl = f & (KCHUNK - 1);
            const float* src = x + (size_t)(m0 + r) * IN_F + kc + cl;
            f32x4 a = *(const f32x4*)src;
            f32x4 b = *(const f32x4*)(src + 4);
            #pragma unroll
            for (int j = 0; j < 4; ++j) {
                xh[r][cl + j]     = (_Float16)a[j];
                xh[r][cl + 4 + j] = (_Float16)b[j];
            }
        }
        __syncthreads();

        #pragma unroll 4
        for (int k0 = 0; k0 < KCHUNK; k0 += 64) {
            half8 alo = *(const half8*)&xh[row][k0 + kg * 8];
            half8 ahi = *(const half8*)&xh[row][k0 + kg * 8 + 32];
            half8 blo = thresh8(wr + kc + k0,      s_in);
            half8 bhi = thresh8(wr + kc + k0 + 32, s_in);
            acc1 = __builtin_amdgcn_mfma_f32_16x16x32_f16(alo, blo, acc1, 0, 0, 0);
            acc1 = __builtin_amdgcn_mfma_f32_16x16x32_f16(ahi, bhi, acc1, 0, 0, 0);
        }
    }

    #pragma unroll
    for (int r = 0; r < 4; ++r)
        xpl[kg * 4 + r][wave * 16 + row] = (_Float16)acc1[r];
    __syncthreads();

    const half8 a_lo = *(const half8*)&xpl[row][kg * 8];
    const half8 a_hi = *(const half8*)&xpl[row][kg * 8 + 32];
    const float scaling = 1.0f / 64.0f;

    for (int c = 0; c < 16; ++c) {
        f32x4 acc[4] = {{0.f,0.f,0.f,0.f},{0.f,0.f,0.f,0.f},
                        {0.f,0.f,0.f,0.f},{0.f,0.f,0.f,0.f}};
        #pragma unroll
        for (int nt = 0; nt < 4; ++nt) {
            const float* wp = w_out
                + (size_t)(c * 256 + wave * 64 + nt * 16 + row) * RANK + kg * 8;
            half8 blo = thresh8(wp,      s_out);
            half8 bhi = thresh8(wp + 32, s_out);
            acc[nt] = __builtin_amdgcn_mfma_f32_16x16x32_f16(a_lo, blo, acc[nt], 0, 0, 0);
            acc[nt] = __builtin_amdgcn_mfma_f32_16x16x32_f16(a_hi, bhi, acc[nt], 0, 0, 0);
        }
        #pragma unroll
        for (int nt = 0; nt < 4; ++nt) {
            const int col = c * 256 + wave * 64 + nt * 16 + row;
            const float b = bias[col];
            #pragma unroll
            for (int r = 0; r < 4; ++r)
                out[(size_t)(m0 + kg * 4 + r) * OUT_F + col] = (acc[nt][r] + b) * scaling;
        }
    }
}

// ---------------------------------------------------------------------------
extern "C" void kernel_launch(void* const* d_in, const int* in_sizes, int n_in,
                              void* d_out, int out_size, void* d_ws, size_t ws_size,
                              hipStream_t stream) {
    (void)in_sizes; (void)n_in; (void)out_size;
    const float* x     = (const float*)d_in[0];
    const float* w_in  = (const float*)d_in[1];
    const float* w_out = (const float*)d_in[2];
    const float* bias  = (const float*)d_in[3];
    const float* s_in  = (const float*)d_in[4];
    const float* s_out = (const float*)d_in[5];

    const size_t need_sw = (size_t)(RANK * IN_F + OUT_F * RANK) * sizeof(_Float16); // 1 MiB

    if (d_ws != nullptr && ws_size >= need_sw) {
        _Float16* sw_in  = (_Float16*)d_ws;
        _Float16* sw_out = sw_in + (size_t)RANK * IN_F;
        prep_kernel<<<(RANK * IN_F + OUT_F * RANK) / 8 / 256, 256, 0, stream>>>(
            w_in, w_out, s_in, s_out, sw_in, sw_out);
        loro_fused_v2<<<M_TOT / 16, 256, 0, stream>>>(
            x, sw_in, sw_out, bias, (float*)d_out);
    } else {
        loro_fallback<<<M_TOT / 16, 256, 0, stream>>>(
            x, w_in, w_out, bias, s_in, s_out, (float*)d_out);
    }
}